// Round 1
// baseline (269.978 us; speedup 1.0000x reference)
//
#include <hip/hip_runtime.h>

#define K_DIM 8192
#define M_REAL 2000
#define N_REAL 2000
#define M_PAD 2048
#define N_PAD 2048

#define BM 256
#define BN 256
#define BK 32
#define SPLITK 4
#define KSLAB (K_DIM / SPLITK)   // 2048
#define NIT (KSLAB / BK)         // 64

typedef __bf16 bf16x8 __attribute__((ext_vector_type(8)));
typedef float f32x4 __attribute__((ext_vector_type(4)));
typedef float fvec4 __attribute__((ext_vector_type(4)));   // for nontemporal builtins

#define RAW_BARRIER()  asm volatile("s_barrier" ::: "memory")
#define WAIT_VM4()     asm volatile("s_waitcnt vmcnt(4)" ::: "memory")
#define WAIT_VM0()     asm volatile("s_waitcnt vmcnt(0)" ::: "memory")

__device__ __forceinline__ unsigned short f2bf(float f) {
    union { float f; unsigned u; } v; v.f = f;
    unsigned r = v.u + 0x7FFFu + ((v.u >> 16) & 1u);  // RNE; inputs are finite normals
    return (unsigned short)(r >> 16);
}

__device__ __forceinline__ unsigned pk2(float a, float b) {
    return (unsigned)f2bf(a) | ((unsigned)f2bf(b) << 16);
}

__device__ __forceinline__ void async16(const void* g, void* l) {
    __builtin_amdgcn_global_load_lds((__attribute__((address_space(1))) void*)(g),
                                     (__attribute__((address_space(3))) void*)(l),
                                     16, 0, 0);
}

// ---------------------------------------------------------------------------
// prep_w: W [2000][8192] f32 -> Wb [2048][8192] bf16 (rows >= 2000 zeroed).
// Grid-stride: 1024 blocks * 256 threads * 8 iters * 8 elems = 2048*8192.
// Per iter: 32 B contiguous load, 16 B contiguous store. 32-bit indexing.
__global__ __launch_bounds__(256) void prep_w(const float* __restrict__ W,
                                              unsigned short* __restrict__ Wb) {
    unsigned tid = blockIdx.x * 256u + threadIdx.x;
#pragma unroll
    for (unsigned i = 0; i < 8; ++i) {
        unsigned e = (i * (1024u * 256u) + tid) * 8u;       // element index
        uint4 o = make_uint4(0u, 0u, 0u, 0u);
        if (e < (unsigned)(M_REAL * K_DIM)) {
            fvec4 f0 = __builtin_nontemporal_load((const fvec4*)(W + e));
            fvec4 f1 = __builtin_nontemporal_load((const fvec4*)(W + e + 4));
            o.x = pk2(f0.x, f0.y);
            o.y = pk2(f0.z, f0.w);
            o.z = pk2(f1.x, f1.y);
            o.w = pk2(f1.z, f1.w);
        }
        *(uint4*)(Wb + e) = o;
    }
}

// ---------------------------------------------------------------------------
// prep_x: X [8192][2000] f32 -> XT [2048][8192] bf16, XT[n][k] = X[k][n],
// n >= 2000 zeroed. 128k x 64n tile per block; 2048 blocks (64 k-tiles * 32 n).
//
// LDS T[n_local][k_local] = u16[64][130]; row stride = 65 words === 1 mod 32.
// Write phase: each thread loads fvec4 from two k-adjacent rows (kl even,
// kl+1), packs per-n into u32, stores word-aligned:
//   bank = (4c + r + const) mod 32 over lanes (c=t&15, r=t>>4) -> all 32 banks,
//   2-way (free, m136). Conflict-free both phases.
// Read phase: 4x u32 -> one 16 B global store; 16 consecutive lanes write
// 256 B contiguous per n-row.
__global__ __launch_bounds__(256) void prep_x(const float* __restrict__ X,
                                              unsigned short* __restrict__ XT) {
    __shared__ unsigned short T[64][130];
    int b = blockIdx.x;
    int k0 = (b & 63) << 7;        // 0..8064 step 128
    int n0 = (b >> 6) << 6;        // 0..1984 step 64
    int t = threadIdx.x;
    int c = t & 15;
    int r = t >> 4;
    int nl = c << 2;               // local n base (x4)
    int n = n0 + nl;
    bool valid = (n < N_REAL);     // n multiple of 4, so n<2000 => n+3 <= 1999
#pragma unroll
    for (int p = 0; p < 4; ++p) {
        int kl = (r << 1) + (p << 5);       // even, covers 0..126
        fvec4 v0 = {0.f, 0.f, 0.f, 0.f};
        fvec4 v1 = {0.f, 0.f, 0.f, 0.f};
        if (valid) {
            v0 = __builtin_nontemporal_load((const fvec4*)(X + (k0 + kl) * N_REAL + n));
            v1 = __builtin_nontemporal_load((const fvec4*)(X + (k0 + kl + 1) * N_REAL + n));
        }
        *(unsigned*)&T[nl + 0][kl] = pk2(v0.x, v1.x);
        *(unsigned*)&T[nl + 1][kl] = pk2(v0.y, v1.y);
        *(unsigned*)&T[nl + 2][kl] = pk2(v0.z, v1.z);
        *(unsigned*)&T[nl + 3][kl] = pk2(v0.w, v1.w);
    }
    __syncthreads();
#pragma unroll
    for (int it = 0; it < 4; ++it) {
        int nl2 = r + (it << 4);            // 0..63
        int kl2 = c << 3;                   // 0..120 step 8
        const unsigned* tp = (const unsigned*)&T[nl2][kl2];
        uint4 o;
        o.x = tp[0]; o.y = tp[1]; o.z = tp[2]; o.w = tp[3];
        *(uint4*)(XT + (((n0 + nl2) << 13) + k0 + kl2)) = o;
    }
}

// ---------------------------------------------------------------------------
// prep_init: out[m][n] = bias[n] for m<2000 (float4 stores, grid-stride).
__global__ __launch_bounds__(256) void prep_init(const float* __restrict__ bias,
                                                 float* __restrict__ out) {
    const int total = M_REAL * (N_REAL / 4);   // 1,000,000 float4
    for (int i = blockIdx.x * 256 + threadIdx.x; i < total; i += 1024 * 256) {
        int m = i / (N_REAL / 4);
        int n4 = i - m * (N_REAL / 4);
        float4 bv = *(const float4*)(bias + (n4 << 2));
        *(float4*)(out + m * N_REAL + (n4 << 2)) = bv;
    }
}

// ---------------------------------------------------------------------------
// Split-K GEMM, 256x256 tile, BK=32, double-buffered LDS with raw s_barrier +
// vmcnt(4). 8 waves x (8x4 MFMA 16x16x32). XCD swizzle: f&7 round-robin.
// UNCHANGED (control).
__global__ __launch_bounds__(512, 2) void gemm_kernel(const unsigned short* __restrict__ Wb,
                                                      const unsigned short* __restrict__ XT,
                                                      float* __restrict__ out) {
    __shared__ __align__(16) unsigned short As[2][BM * BK];  // 2 x 16 KB
    __shared__ __align__(16) unsigned short Bs[2][BN * BK];  // 2 x 16 KB

    int f = blockIdx.x;
    int xcd = f & 7;
    int local = f >> 3;                    // 0..31
    int bz = local & 3;
    int bx = (xcd & 3) * 2 + ((local >> 2) & 1);   // 0..7
    int by = (xcd >> 2) * 4 + (local >> 3);        // 0..7

    int t = threadIdx.x;
    int w = t >> 6;              // 0..7
    int l = t & 63;
    int wm = (w >> 2) * 128;     // 0 or 128
    int wn = (w & 3) * 64;       // 0,64,128,192
    int lane16 = l & 15;
    int quad = l >> 4;
    int m0 = by * BM;
    int n0 = bx * BN;
    int ks = bz * KSLAB;

    f32x4 acc[8][4] = {};

    int srow = l >> 2;
    int scol = (l & 3) * 8;
    int rb = w * 32;
    const unsigned short* gA0 = Wb + (long long)(m0 + rb + srow) * K_DIM + ks + scol;
    const unsigned short* gA1 = gA0 + 16LL * K_DIM;
    const unsigned short* gB0 = XT + (long long)(n0 + rb + srow) * K_DIM + ks + scol;
    const unsigned short* gB1 = gB0 + 16LL * K_DIM;

    async16(gA0, &As[0][rb * BK]);
    async16(gA1, &As[0][(rb + 16) * BK]);
    async16(gB0, &Bs[0][rb * BK]);
    async16(gB1, &Bs[0][(rb + 16) * BK]);
    gA0 += BK; gA1 += BK; gB0 += BK; gB1 += BK;

    for (int kt = 0; kt < NIT; ++kt) {
        int cur = kt & 1;
        if (kt + 1 < NIT) {
            int nxt = cur ^ 1;
            async16(gA0, &As[nxt][rb * BK]);
            async16(gA1, &As[nxt][(rb + 16) * BK]);
            async16(gB0, &Bs[nxt][rb * BK]);
            async16(gB1, &Bs[nxt][(rb + 16) * BK]);
            gA0 += BK; gA1 += BK; gB0 += BK; gB1 += BK;
            WAIT_VM4();
        } else {
            WAIT_VM0();
        }
        RAW_BARRIER();

        bf16x8 a[8], b[4];
#pragma unroll
        for (int i = 0; i < 8; ++i)
            a[i] = *(const bf16x8*)&As[cur][(wm + i * 16 + lane16) * BK + quad * 8];
#pragma unroll
        for (int j = 0; j < 4; ++j)
            b[j] = *(const bf16x8*)&Bs[cur][(wn + j * 16 + lane16) * BK + quad * 8];

#pragma unroll
        for (int i = 0; i < 8; ++i)
#pragma unroll
            for (int j = 0; j < 4; ++j)
                acc[i][j] = __builtin_amdgcn_mfma_f32_16x16x32_bf16(a[i], b[j], acc[i][j], 0, 0, 0);

        if (kt + 1 < NIT)
            RAW_BARRIER();
    }

    // Epilogue: C/D layout col = lane&15, row = quad*4 + reg  [m89-verified]
#pragma unroll
    for (int j = 0; j < 4; ++j) {
        int n = n0 + wn + j * 16 + lane16;
        if (n >= N_REAL) continue;
#pragma unroll
        for (int i = 0; i < 8; ++i) {
            int mbase = m0 + wm + i * 16 + quad * 4;
#pragma unroll
            for (int r = 0; r < 4; ++r) {
                int m = mbase + r;
                if (m < M_REAL)
                    atomicAdd(&out[(long long)m * N_REAL + n], acc[i][j][r]);
            }
        }
    }
}

// ---------------------------------------------------------------------------
extern "C" void kernel_launch(void* const* d_in, const int* in_sizes, int n_in,
                              void* d_out, int out_size, void* d_ws, size_t ws_size,
                              hipStream_t stream) {
    const float* W    = (const float*)d_in[0];  // [2000][8192]
    const float* bias = (const float*)d_in[1];  // [2000]
    const float* X    = (const float*)d_in[2];  // [8192][2000]
    float* out = (float*)d_out;

    unsigned short* Wb = (unsigned short*)d_ws;                 // [2048][8192] bf16
    unsigned short* XT = Wb + (long long)M_PAD * K_DIM;         // [2048][8192] bf16

    prep_w<<<1024, 256, 0, stream>>>(W, Wb);
    prep_x<<<2048, 256, 0, stream>>>(X, XT);
    prep_init<<<1024, 256, 0, stream>>>(bias, out);

    gemm_kernel<<<(N_PAD / BN) * (M_PAD / BM) * SPLITK, 512, 0, stream>>>(Wb, XT, out);
}

// Round 2
// 260.341 us; speedup vs baseline: 1.0370x; 1.0370x over previous
//
#include <hip/hip_runtime.h>

#define K_DIM 8192
#define M_REAL 2000
#define N_REAL 2000
#define M_PAD 2048
#define N_PAD 2048

#define BM 256
#define BN 256
#define BK 32
#define SPLITK 4
#define KSLAB (K_DIM / SPLITK)   // 2048
#define NSTEP (KSLAB / BK)       // 64 K-steps per block

// fused prep block ranges
#define NB_W 1024
#define NB_X 2048
#define NB_I 256

typedef __bf16 bf16x8 __attribute__((ext_vector_type(8)));
typedef float f32x4 __attribute__((ext_vector_type(4)));
typedef float fvec4 __attribute__((ext_vector_type(4)));

#define RAW_BARRIER()  asm volatile("s_barrier" ::: "memory")
#define LGKM0()        asm volatile("s_waitcnt lgkmcnt(0)" ::: "memory")
#define WAIT_VM8()     asm volatile("s_waitcnt vmcnt(8)" ::: "memory")
#define WAIT_VM4()     asm volatile("s_waitcnt vmcnt(4)" ::: "memory")
#define WAIT_VM0()     asm volatile("s_waitcnt vmcnt(0)" ::: "memory")

__device__ __forceinline__ unsigned short f2bf(float f) {
    union { float f; unsigned u; } v; v.f = f;
    unsigned r = v.u + 0x7FFFu + ((v.u >> 16) & 1u);  // RNE; inputs are finite normals
    return (unsigned short)(r >> 16);
}

__device__ __forceinline__ unsigned pk2(float a, float b) {
    return (unsigned)f2bf(a) | ((unsigned)f2bf(b) << 16);
}

__device__ __forceinline__ void async16(const void* g, void* l) {
    __builtin_amdgcn_global_load_lds((__attribute__((address_space(1))) void*)(g),
                                     (__attribute__((address_space(3))) void*)(l),
                                     16, 0, 0);
}

// ---------------------------------------------------------------------------
// Fused prep (ONE dispatch so its cost is visible in the top-5 counter table):
//   blocks [0,1024):       W f32 -> Wb bf16 [2048][8192], grid-stride, 32B ld/16B st
//   blocks [1024,3072):    X [8192][2000] f32 -> XT bf16 [2048][8192] transpose,
//                          conflict-free LDS (row stride 65 words === 1 mod 32)
//   blocks [3072,3328):    out[m][n] = bias[n] (float4 stores, grid-stride)
__global__ __launch_bounds__(256) void prep_kernel(const float* __restrict__ W,
                                                   const float* __restrict__ X,
                                                   const float* __restrict__ bias,
                                                   unsigned short* __restrict__ Wb,
                                                   unsigned short* __restrict__ XT,
                                                   float* __restrict__ out) {
    __shared__ unsigned short T[64][130];
    int bid = blockIdx.x;
    if (bid < NB_W) {
        unsigned tid = bid * 256u + threadIdx.x;
#pragma unroll
        for (unsigned i = 0; i < 8; ++i) {
            unsigned e = (i * (1024u * 256u) + tid) * 8u;       // element index
            uint4 o = make_uint4(0u, 0u, 0u, 0u);
            if (e < (unsigned)(M_REAL * K_DIM)) {
                fvec4 f0 = __builtin_nontemporal_load((const fvec4*)(W + e));
                fvec4 f1 = __builtin_nontemporal_load((const fvec4*)(W + e + 4));
                o.x = pk2(f0.x, f0.y);
                o.y = pk2(f0.z, f0.w);
                o.z = pk2(f1.x, f1.y);
                o.w = pk2(f1.z, f1.w);
            }
            *(uint4*)(Wb + e) = o;
        }
    } else if (bid < NB_W + NB_X) {
        int b = bid - NB_W;
        int k0 = (b & 63) << 7;        // 0..8064 step 128
        int n0 = (b >> 6) << 6;        // 0..1984 step 64
        int t = threadIdx.x;
        int c = t & 15;
        int r = t >> 4;
        int nl = c << 2;               // local n base (x4)
        int n = n0 + nl;
        bool valid = (n < N_REAL);
#pragma unroll
        for (int p = 0; p < 4; ++p) {
            int kl = (r << 1) + (p << 5);
            fvec4 v0 = {0.f, 0.f, 0.f, 0.f};
            fvec4 v1 = {0.f, 0.f, 0.f, 0.f};
            if (valid) {
                v0 = __builtin_nontemporal_load((const fvec4*)(X + (k0 + kl) * N_REAL + n));
                v1 = __builtin_nontemporal_load((const fvec4*)(X + (k0 + kl + 1) * N_REAL + n));
            }
            *(unsigned*)&T[nl + 0][kl] = pk2(v0.x, v1.x);
            *(unsigned*)&T[nl + 1][kl] = pk2(v0.y, v1.y);
            *(unsigned*)&T[nl + 2][kl] = pk2(v0.z, v1.z);
            *(unsigned*)&T[nl + 3][kl] = pk2(v0.w, v1.w);
        }
        __syncthreads();
#pragma unroll
        for (int it = 0; it < 4; ++it) {
            int nl2 = r + (it << 4);
            int kl2 = c << 3;
            const unsigned* tp = (const unsigned*)&T[nl2][kl2];
            uint4 o;
            o.x = tp[0]; o.y = tp[1]; o.z = tp[2]; o.w = tp[3];
            *(uint4*)(XT + (((n0 + nl2) << 13) + k0 + kl2)) = o;
        }
    } else {
        const int total = M_REAL * (N_REAL / 4);   // 1,000,000 float4
        for (int i = (bid - NB_W - NB_X) * 256 + (int)threadIdx.x; i < total; i += NB_I * 256) {
            int m = i / (N_REAL / 4);
            int n4 = i - m * (N_REAL / 4);
            float4 bv = *(const float4*)(bias + (n4 << 2));
            *(float4*)(out + m * N_REAL + (n4 << 2)) = bv;
        }
    }
}

// ---------------------------------------------------------------------------
// Split-K GEMM, 256x256 tile, BK=32, 4-deep LDS pipeline (128 KiB), phase-
// interleaved schedule (T3+T4): per K-step two phases, each
//   { ds_read frags | 2x global_load_lds (step s+3) | barrier | lgkmcnt(0) |
//     setprio(1) 16x MFMA setprio(0) | barrier }
// Counted vmcnt(8) once per K-step (never 0 in main loop); tail peels 4->0.
// T2 LDS swizzle: chunk ^= (row&3) (16B chunks within 64B row), applied BOTH
// on the pre-swizzled global source of global_load_lds and on the ds_read
// address (rule #21) -> uniform 8 words/bank on every ds_read_b128.
//
// Race-freedom: buffer written at step s is (s+3)&3 == (s-1)&3, last read at
// step s-1; every wave's reads completed before s-1's final barrier
// (lgkmcnt(0) precedes MFMA precedes barrier), and stores issue after it.
// vmcnt(8): the 8 newest loads are exactly steps s+2,s+3 -> step s+1 landed.
__global__ __launch_bounds__(512, 2) void gemm_kernel(const unsigned short* __restrict__ Wb,
                                                      const unsigned short* __restrict__ XT,
                                                      float* __restrict__ out) {
    __shared__ __align__(16) unsigned short As[4][BM * BK];  // 4 x 16 KB
    __shared__ __align__(16) unsigned short Bs[4][BN * BK];  // 4 x 16 KB

    int f = blockIdx.x;
    int xcd = f & 7;
    int local = f >> 3;                    // 0..31
    int bz = local & 3;
    int bx = (xcd & 3) * 2 + ((local >> 2) & 1);   // 0..7
    int by = (xcd >> 2) * 4 + (local >> 3);        // 0..7

    int t = threadIdx.x;
    int w = t >> 6;              // 0..7
    int l = t & 63;
    int wm = (w >> 2) * 128;     // 0 or 128
    int wn = (w & 3) * 64;       // 0,64,128,192
    int lane16 = l & 15;
    int quad = l >> 4;
    int m0 = by * BM;
    int n0 = bx * BN;
    int ks = bz * KSLAB;

    f32x4 acc[8][4] = {};

    // ---- staging source pointers (pre-swizzled chunk within each 64B row) ----
    int rlin = t >> 2;                       // 0..127 (round-0 row; round1 = +128)
    int ck = (t & 3) ^ (rlin & 3);           // 16B chunk index, swizzled
    const unsigned short* gA0 = Wb + (long long)(m0 + rlin) * K_DIM + ks + ck * 8;
    const unsigned short* gA1 = gA0 + 128LL * K_DIM;
    const unsigned short* gB0 = XT + (long long)(n0 + rlin) * K_DIM + ks + ck * 8;
    const unsigned short* gB1 = gB0 + 128LL * K_DIM;

    char* smA = (char*)&As[0][0];
    char* smB = (char*)&Bs[0][0];
    int wslot = w * 1024;                    // wave-uniform LDS slot within a round

#define STAGE_A(OFF) do { \
        async16(gA0, smA + (OFF) + wslot); \
        async16(gA1, smA + (OFF) + 8192 + wslot); \
        gA0 += BK; gA1 += BK; } while (0)
#define STAGE_B(OFF) do { \
        async16(gB0, smB + (OFF) + wslot); \
        async16(gB1, smB + (OFF) + 8192 + wslot); \
        gB0 += BK; gB1 += BK; } while (0)

    // ---- reader-side swizzled row offsets (bytes within one 16 KB buffer) ----
    int swz = ((quad ^ (lane16 & 3)) << 4);          // 16B chunk swizzle
    int arow = (wm + lane16) * 64 + swz;
    int brow = (wn + lane16) * 64 + swz;

    // ---- prologue: stage K-steps 0,1,2 (12 loads), wait for step 0 ----
    STAGE_A(0);     STAGE_B(0);
    STAGE_A(16384); STAGE_B(16384);
    STAGE_A(32768); STAGE_B(32768);
    WAIT_VM8();                      // 8 newest = steps 1,2 -> step 0 landed
    RAW_BARRIER();

    int cur = 0;
    int stg = 49152;

    bf16x8 a0, a1, a2, a3, b0, b1, b2, b3;

    for (int s = 0; s < NSTEP; ++s) {
        // ---------------- phase 1: i0-3 x j0-3 ----------------
        {
            const char* ab = smA + cur + arow;
            const char* bb = smB + cur + brow;
            a0 = *(const bf16x8*)(ab);
            a1 = *(const bf16x8*)(ab + 1024);
            a2 = *(const bf16x8*)(ab + 2048);
            a3 = *(const bf16x8*)(ab + 3072);
            b0 = *(const bf16x8*)(bb);
            b1 = *(const bf16x8*)(bb + 1024);
            b2 = *(const bf16x8*)(bb + 2048);
            b3 = *(const bf16x8*)(bb + 3072);
            if (s < NSTEP - 3) STAGE_A(stg);
            RAW_BARRIER();
            LGKM0();
            __builtin_amdgcn_s_setprio(1);
            acc[0][0] = __builtin_amdgcn_mfma_f32_16x16x32_bf16(a0, b0, acc[0][0], 0, 0, 0);
            acc[0][1] = __builtin_amdgcn_mfma_f32_16x16x32_bf16(a0, b1, acc[0][1], 0, 0, 0);
            acc[0][2] = __builtin_amdgcn_mfma_f32_16x16x32_bf16(a0, b2, acc[0][2], 0, 0, 0);
            acc[0][3] = __builtin_amdgcn_mfma_f32_16x16x32_bf16(a0, b3, acc[0][3], 0, 0, 0);
            acc[1][0] = __builtin_amdgcn_mfma_f32_16x16x32_bf16(a1, b0, acc[1][0], 0, 0, 0);
            acc[1][1] = __builtin_amdgcn_mfma_f32_16x16x32_bf16(a1, b1, acc[1][1], 0, 0, 0);
            acc[1][2] = __builtin_amdgcn_mfma_f32_16x16x32_bf16(a1, b2, acc[1][2], 0, 0, 0);
            acc[1][3] = __builtin_amdgcn_mfma_f32_16x16x32_bf16(a1, b3, acc[1][3], 0, 0, 0);
            acc[2][0] = __builtin_amdgcn_mfma_f32_16x16x32_bf16(a2, b0, acc[2][0], 0, 0, 0);
            acc[2][1] = __builtin_amdgcn_mfma_f32_16x16x32_bf16(a2, b1, acc[2][1], 0, 0, 0);
            acc[2][2] = __builtin_amdgcn_mfma_f32_16x16x32_bf16(a2, b2, acc[2][2], 0, 0, 0);
            acc[2][3] = __builtin_amdgcn_mfma_f32_16x16x32_bf16(a2, b3, acc[2][3], 0, 0, 0);
            acc[3][0] = __builtin_amdgcn_mfma_f32_16x16x32_bf16(a3, b0, acc[3][0], 0, 0, 0);
            acc[3][1] = __builtin_amdgcn_mfma_f32_16x16x32_bf16(a3, b1, acc[3][1], 0, 0, 0);
            acc[3][2] = __builtin_amdgcn_mfma_f32_16x16x32_bf16(a3, b2, acc[3][2], 0, 0, 0);
            acc[3][3] = __builtin_amdgcn_mfma_f32_16x16x32_bf16(a3, b3, acc[3][3], 0, 0, 0);
            __builtin_amdgcn_s_setprio(0);
            RAW_BARRIER();
        }
        // ---------------- phase 2: i4-7 x j0-3 ----------------
        {
            const char* ab = smA + cur + arow + 4096;
            a0 = *(const bf16x8*)(ab);
            a1 = *(const bf16x8*)(ab + 1024);
            a2 = *(const bf16x8*)(ab + 2048);
            a3 = *(const bf16x8*)(ab + 3072);
            if (s < NSTEP - 3) {
                STAGE_B(stg);
                WAIT_VM8();          // 8 newest = steps s+2,s+3 -> s+1 landed
            } else if (s == NSTEP - 3) {
                WAIT_VM4();          // 4 newest = step 63 -> step 62 landed
            } else if (s == NSTEP - 2) {
                WAIT_VM0();          // step 63 landed
            }
            RAW_BARRIER();
            LGKM0();
            __builtin_amdgcn_s_setprio(1);
            acc[4][0] = __builtin_amdgcn_mfma_f32_16x16x32_bf16(a0, b0, acc[4][0], 0, 0, 0);
            acc[4][1] = __builtin_amdgcn_mfma_f32_16x16x32_bf16(a0, b1, acc[4][1], 0, 0, 0);
            acc[4][2] = __builtin_amdgcn_mfma_f32_16x16x32_bf16(a0, b2, acc[4][2], 0, 0, 0);
            acc[4][3] = __builtin_amdgcn_mfma_f32_16x16x32_bf16(a0, b3, acc[4][3], 0, 0, 0);
            acc[5][0] = __builtin_amdgcn_mfma_f32_16x16x32_bf16(a1, b0, acc[5][0], 0, 0, 0);
            acc[5][1] = __builtin_amdgcn_mfma_f32_16x16x32_bf16(a1, b1, acc[5][1], 0, 0, 0);
            acc[5][2] = __builtin_amdgcn_mfma_f32_16x16x32_bf16(a1, b2, acc[5][2], 0, 0, 0);
            acc[5][3] = __builtin_amdgcn_mfma_f32_16x16x32_bf16(a1, b3, acc[5][3], 0, 0, 0);
            acc[6][0] = __builtin_amdgcn_mfma_f32_16x16x32_bf16(a2, b0, acc[6][0], 0, 0, 0);
            acc[6][1] = __builtin_amdgcn_mfma_f32_16x16x32_bf16(a2, b1, acc[6][1], 0, 0, 0);
            acc[6][2] = __builtin_amdgcn_mfma_f32_16x16x32_bf16(a2, b2, acc[6][2], 0, 0, 0);
            acc[6][3] = __builtin_amdgcn_mfma_f32_16x16x32_bf16(a2, b3, acc[6][3], 0, 0, 0);
            acc[7][0] = __builtin_amdgcn_mfma_f32_16x16x32_bf16(a3, b0, acc[7][0], 0, 0, 0);
            acc[7][1] = __builtin_amdgcn_mfma_f32_16x16x32_bf16(a3, b1, acc[7][1], 0, 0, 0);
            acc[7][2] = __builtin_amdgcn_mfma_f32_16x16x32_bf16(a3, b2, acc[7][2], 0, 0, 0);
            acc[7][3] = __builtin_amdgcn_mfma_f32_16x16x32_bf16(a3, b3, acc[7][3], 0, 0, 0);
            __builtin_amdgcn_s_setprio(0);
            RAW_BARRIER();
        }
        cur = (cur + 16384) & 65535;
        stg = (stg + 16384) & 65535;
    }
#undef STAGE_A
#undef STAGE_B

    // Epilogue: C/D layout col = lane&15, row = quad*4 + reg  [m89-verified]
#pragma unroll
    for (int j = 0; j < 4; ++j) {
        int n = n0 + wn + j * 16 + lane16;
        if (n >= N_REAL) continue;
#pragma unroll
        for (int i = 0; i < 8; ++i) {
            int mbase = m0 + wm + i * 16 + quad * 4;
#pragma unroll
            for (int r = 0; r < 4; ++r) {
                int m = mbase + r;
                if (m < M_REAL)
                    atomicAdd(&out[(long long)m * N_REAL + n], acc[i][j][r]);
            }
        }
    }
}

// ---------------------------------------------------------------------------
extern "C" void kernel_launch(void* const* d_in, const int* in_sizes, int n_in,
                              void* d_out, int out_size, void* d_ws, size_t ws_size,
                              hipStream_t stream) {
    const float* W    = (const float*)d_in[0];  // [2000][8192]
    const float* bias = (const float*)d_in[1];  // [2000]
    const float* X    = (const float*)d_in[2];  // [8192][2000]
    float* out = (float*)d_out;

    unsigned short* Wb = (unsigned short*)d_ws;                 // [2048][8192] bf16
    unsigned short* XT = Wb + (long long)M_PAD * K_DIM;         // [2048][8192] bf16

    prep_kernel<<<NB_W + NB_X + NB_I, 256, 0, stream>>>(W, X, bias, Wb, XT, out);

    gemm_kernel<<<(N_PAD / BN) * (M_PAD / BM) * SPLITK, 512, 0, stream>>>(Wb, XT, out);
}